// Round 7
// baseline (346.289 us; speedup 1.0000x reference)
//
#include <hip/hip_runtime.h>

#define S_LEN 2048
#define D_DIM 128

typedef float f4 __attribute__((ext_vector_type(4)));
typedef __bf16 y8 __attribute__((ext_vector_type(8)));
typedef short s4v __attribute__((ext_vector_type(4)));

union Frag {
  unsigned u[4];
  unsigned short h[8];
  y8 v;
};

// round-to-nearest-even f32 -> bf16 (verified in round 1)
__device__ __forceinline__ unsigned short f2bf(float f) {
  unsigned u = __float_as_uint(f);
  return (unsigned short)((u + 0x7fffu + ((u >> 16) & 1u)) >> 16);
}

// Flash-attention fwd, causal. Round-1-verified per-tile math (16x16x32 MFMA,
// swapped QK^T, shuffle softmax/P-redistribution) inside a pipelined structure:
// KVBLK=64, double-buffered LDS, one barrier per tile, heavy-first blocks.
__global__ __launch_bounds__(256, 2) void fattn_kernel(
    const float* __restrict__ Qg0, const float* __restrict__ Kg0,
    const float* __restrict__ Vg0, float* __restrict__ Og0) {
  // K tile [64][128] bf16, short-index swizzle ^((row&7)<<3); double buffered
  __shared__ __align__(16) unsigned short kbuf[2][64 * 128];
  // V tile transposed [d=128][k=64] bf16, same swizzle on k; double buffered
  __shared__ __align__(16) unsigned short vtbuf[2][128 * 64];

  const int qb  = 31 - (int)blockIdx.x;  // heavy q-tiles first
  const int bh  = blockIdx.y;            // b*H + h
  const int tid = threadIdx.x;
  const int w   = tid >> 6;
  const int l   = tid & 63;
  const int g   = l >> 4;                // 16-lane group 0..3
  const int qi  = l & 15;

  const int wq    = qb * 64 + w * 16;    // wave's first q row
  const int q_abs = wq + qi;             // this lane's softmax row

  const size_t base = (size_t)bh * (S_LEN * D_DIM);
  const float* Qg = Qg0 + base;
  const float* Kg = Kg0 + base;
  const float* Vg = Vg0 + base;
  float*       Og = Og0 + base;

  // ---- Q fragments in registers (scaled by 1/sqrt(D)) — round-1 verbatim ----
  Frag qf[4];
  {
    const float sc = 0.08838834764831845f;  // 1/sqrt(128)
    const float* qrow = Qg + (size_t)q_abs * D_DIM + g * 8;
#pragma unroll
    for (int c = 0; c < 4; ++c) {
      float4 f0 = *(const float4*)(qrow + c * 32);
      float4 f1 = *(const float4*)(qrow + c * 32 + 4);
      qf[c].h[0] = f2bf(f0.x * sc); qf[c].h[1] = f2bf(f0.y * sc);
      qf[c].h[2] = f2bf(f0.z * sc); qf[c].h[3] = f2bf(f0.w * sc);
      qf[c].h[4] = f2bf(f1.x * sc); qf[c].h[5] = f2bf(f1.y * sc);
      qf[c].h[6] = f2bf(f1.z * sc); qf[c].h[7] = f2bf(f1.w * sc);
    }
  }

  f4 acc[8];
#pragma unroll
  for (int i = 0; i < 8; ++i) acc[i] = (f4){0.f, 0.f, 0.f, 0.f};
  float m_run = -3.0e38f;
  float l_run = 0.f;

  const int nt = qb + 1;  // 64-k tiles covering k <= qb*64+63

  // ---- staging (f32 global -> bf16 LDS, swizzled); round-1 layouts, 64-k extent ----
  auto stage = [&](int tt, int b) {
    const int kb = tt * 64;
    // K: 1024 chunks of 8 floats
#pragma unroll
    for (int it = 0; it < 4; ++it) {
      const int chunk = it * 256 + tid;
      const int kk = chunk >> 4;   // row 0..63
      const int c8 = chunk & 15;   // 8-float group
      const float* src = Kg + (size_t)(kb + kk) * D_DIM + c8 * 8;
      float4 f0 = *(const float4*)src;
      float4 f1 = *(const float4*)(src + 4);
      Frag t2;
      t2.h[0] = f2bf(f0.x); t2.h[1] = f2bf(f0.y); t2.h[2] = f2bf(f0.z); t2.h[3] = f2bf(f0.w);
      t2.h[4] = f2bf(f1.x); t2.h[5] = f2bf(f1.y); t2.h[6] = f2bf(f1.z); t2.h[7] = f2bf(f1.w);
      *(y8*)&kbuf[b][kk * 128 + ((c8 * 8) ^ ((kk & 7) << 3))] = t2.v;
    }
    // V: 512 4x4 blocks, transposed into vtbuf[d][k], same XOR swizzle on k
#pragma unroll
    for (int it = 0; it < 2; ++it) {
      const int bid = it * 256 + tid;
      const int d0 = (bid & 31) * 4;
      const int k0 = (bid >> 5) * 4;
      const float* vsrc = Vg + (size_t)(kb + k0) * D_DIM + d0;
      float4 r0 = *(const float4*)(vsrc);
      float4 r1 = *(const float4*)(vsrc + D_DIM);
      float4 r2 = *(const float4*)(vsrc + 2 * D_DIM);
      float4 r3 = *(const float4*)(vsrc + 3 * D_DIM);
      *(s4v*)&vtbuf[b][(d0 + 0) * 64 + (k0 ^ (((d0 + 0) & 7) << 3))] =
          (s4v){(short)f2bf(r0.x), (short)f2bf(r1.x), (short)f2bf(r2.x), (short)f2bf(r3.x)};
      *(s4v*)&vtbuf[b][(d0 + 1) * 64 + (k0 ^ (((d0 + 1) & 7) << 3))] =
          (s4v){(short)f2bf(r0.y), (short)f2bf(r1.y), (short)f2bf(r2.y), (short)f2bf(r3.y)};
      *(s4v*)&vtbuf[b][(d0 + 2) * 64 + (k0 ^ (((d0 + 2) & 7) << 3))] =
          (s4v){(short)f2bf(r0.z), (short)f2bf(r1.z), (short)f2bf(r2.z), (short)f2bf(r3.z)};
      *(s4v*)&vtbuf[b][(d0 + 3) * 64 + (k0 ^ (((d0 + 3) & 7) << 3))] =
          (s4v){(short)f2bf(r0.w), (short)f2bf(r1.w), (short)f2bf(r2.w), (short)f2bf(r3.w)};
    }
  };

  stage(0, 0);
  __syncthreads();
  int cur = 0;

  for (int t = 0; t < nt; ++t) {
    if (t + 1 < nt) stage(t + 1, cur ^ 1);  // overlap next-tile loads with compute

    const int kb = t * 64;
    const unsigned short* kp = kbuf[cur];
    const unsigned short* vp = vtbuf[cur];

#pragma unroll
    for (int s = 0; s < 2; ++s) {
      const int kbs = kb + 32 * s;
      if (kbs > wq + 15) continue;  // sub-tile entirely future for this wave

      // ---- QK^T: S^T[k][q] over 4 d-chunks (round-1 verbatim, +32s row offset) ----
      f4 s0 = (f4){0.f, 0.f, 0.f, 0.f};  // k rows 0..15 of sub-tile
      f4 s1 = (f4){0.f, 0.f, 0.f, 0.f};  // k rows 16..31
#pragma unroll
      for (int c = 0; c < 4; ++c) {
        const int so = (c * 32 + g * 8) ^ ((qi & 7) << 3);
        y8 a0 = *(const y8*)&kp[(32 * s + qi) * 128 + so];
        y8 a1 = *(const y8*)&kp[(32 * s + qi + 16) * 128 + so];
        s0 = __builtin_amdgcn_mfma_f32_16x16x32_bf16(a0, qf[c].v, s0, 0, 0, 0);
        s1 = __builtin_amdgcn_mfma_f32_16x16x32_bf16(a1, qf[c].v, s1, 0, 0, 0);
      }

      // ---- causal mask (diagonal sub-tiles only; gate on wave MIN q) ----
      if (kbs + 31 > wq) {
        const int kl = kbs + g * 4;
#pragma unroll
        for (int r = 0; r < 4; ++r) {
          if (kl + r > q_abs)      s0[r] = -3.0e38f;
          if (kl + 16 + r > q_abs) s1[r] = -3.0e38f;
        }
      }

      // ---- online softmax (round-1 verbatim) ----
      float tmax = fmaxf(fmaxf(fmaxf(s0[0], s0[1]), fmaxf(s0[2], s0[3])),
                         fmaxf(fmaxf(s1[0], s1[1]), fmaxf(s1[2], s1[3])));
      tmax = fmaxf(tmax, __shfl_xor(tmax, 16));
      tmax = fmaxf(tmax, __shfl_xor(tmax, 32));
      const float mnew = fmaxf(m_run, tmax);
      const float scl  = __expf(m_run - mnew);
      float p0 = __expf(s0[0] - mnew), p1 = __expf(s0[1] - mnew);
      float p2 = __expf(s0[2] - mnew), p3 = __expf(s0[3] - mnew);
      float p4 = __expf(s1[0] - mnew), p5 = __expf(s1[1] - mnew);
      float p6 = __expf(s1[2] - mnew), p7 = __expf(s1[3] - mnew);
      float rs = ((p0 + p1) + (p2 + p3)) + ((p4 + p5) + (p6 + p7));
      rs += __shfl_xor(rs, 16);
      rs += __shfl_xor(rs, 32);
      l_run = l_run * scl + rs;
      m_run = mnew;

      f4 srv;
      srv[0] = __shfl(scl, g * 4 + 0);
      srv[1] = __shfl(scl, g * 4 + 1);
      srv[2] = __shfl(scl, g * 4 + 2);
      srv[3] = __shfl(scl, g * 4 + 3);
#pragma unroll
      for (int ch = 0; ch < 8; ++ch) acc[ch] *= srv;

      // ---- P redistribution (round-1 verbatim) ----
      const unsigned w0 = (unsigned)f2bf(p0) | ((unsigned)f2bf(p1) << 16);
      const unsigned w1 = (unsigned)f2bf(p2) | ((unsigned)f2bf(p3) << 16);
      const unsigned w2 = (unsigned)f2bf(p4) | ((unsigned)f2bf(p5) << 16);
      const unsigned w3 = (unsigned)f2bf(p6) | ((unsigned)f2bf(p7) << 16);
      const int  bs = ((l >> 4) & 1) * 32 + qi;
      const bool hb = (l >= 32);
      unsigned t0  = __shfl(w0, bs),      t2  = __shfl(w2, bs);
      unsigned t1  = __shfl(w1, bs),      t3  = __shfl(w3, bs);
      unsigned t0b = __shfl(w0, bs + 16), t2b = __shfl(w2, bs + 16);
      unsigned t1b = __shfl(w1, bs + 16), t3b = __shfl(w3, bs + 16);
      Frag pa;
      pa.u[0] = hb ? t2  : t0;
      pa.u[1] = hb ? t3  : t1;
      pa.u[2] = hb ? t2b : t0b;
      pa.u[3] = hb ? t3b : t1b;

      // ---- PV (round-1 verbatim, swizzled vtbuf read, +32s col offset) ----
#pragma unroll
      for (int ch = 0; ch < 8; ++ch) {
        y8 bv = *(const y8*)&vp[(ch * 16 + qi) * 64 + ((32 * s + g * 8) ^ ((qi & 7) << 3))];
        acc[ch] = __builtin_amdgcn_mfma_f32_16x16x32_bf16(pa.v, bv, acc[ch], 0, 0, 0);
      }
    }

    __syncthreads();
    cur ^= 1;
  }

  // ---- epilogue (round-1 verbatim) ----
  f4 li;
  li[0] = 1.0f / __shfl(l_run, g * 4 + 0);
  li[1] = 1.0f / __shfl(l_run, g * 4 + 1);
  li[2] = 1.0f / __shfl(l_run, g * 4 + 2);
  li[3] = 1.0f / __shfl(l_run, g * 4 + 3);
#pragma unroll
  for (int ch = 0; ch < 8; ++ch) {
#pragma unroll
    for (int r = 0; r < 4; ++r) {
      Og[(size_t)(wq + g * 4 + r) * D_DIM + ch * 16 + qi] = acc[ch][r] * li[r];
    }
  }
}

extern "C" void kernel_launch(void* const* d_in, const int* in_sizes, int n_in,
                              void* d_out, int out_size, void* d_ws, size_t ws_size,
                              hipStream_t stream) {
  const float* Q = (const float*)d_in[0];
  const float* K = (const float*)d_in[1];
  const float* V = (const float*)d_in[2];
  // d_in[3] (causal triu mask) semantics hardcoded in-kernel
  float* O = (float*)d_out;
  dim3 grid(S_LEN / 64, 32);  // (q-tile of 64, b*h)
  fattn_kernel<<<grid, 256, 0, stream>>>(Q, K, V, O);
}